// Round 1
// 456.286 us; speedup vs baseline: 1.0200x; 1.0200x over previous
//
#include <hip/hip_runtime.h>

#define H 128          // hidden dim (fixed by problem)
#define CAP 64         // max edges per (rel,dst) bucket

typedef _Float16 f16x8 __attribute__((ext_vector_type(8)));
typedef float    f32x4 __attribute__((ext_vector_type(4)));

// ---------------- edge bucketing: one pass, reused by both layers ----------------
__global__ __launch_bounds__(256) void hist_fill(const int* __restrict__ src,
    const int* __restrict__ dst, const int* __restrict__ et,
    int* __restrict__ cnt, int* __restrict__ elist, int E, int N)
{
    int e = blockIdx.x * 256 + threadIdx.x;
    if (e >= E) return;
    int s = src[e], d = dst[e], t = et[e];
    int b = t * N + d;
    int pos = atomicAdd(&cnt[b], 1);
    if (pos < CAP) elist[(size_t)b * CAP + pos] = s;
}

// ---------------- weight prep ----------------
// wInT: packed MFMA-B-fragment order: wpk[((k>>3)*H + c)*8 + (k&7)] = w_in[k*H+c]
// so a wave's B-frag load (lane l15=col, q=k-group) is 4x256B contiguous segments.
// w3T: plain [col][k] transpose (consumed from regs in gemm3, layout unchanged).
__global__ __launch_bounds__(256) void prep_w(const float* __restrict__ w_in,
    const float* __restrict__ w_root, const float* __restrict__ w_rel,
    _Float16* __restrict__ wInT, _Float16* __restrict__ w3T, int K)
{
    int idx = blockIdx.x * 256 + threadIdx.x;
    int tot1 = K * H;
    if (idx < tot1) {
        int k = idx >> 7, c = idx & 127;               // input order: coalesced read
        int o = ((k >> 3) << 10) + (c << 3) + (k & 7); // ((k/8)*H + c)*8 + k%8
        wInT[o] = (_Float16)w_in[idx];
    } else {
        int i2 = idx - tot1;
        if (i2 < 3 * H * H) {
            int m = i2 / (H * H), r2 = i2 - m * (H * H);
            int c = r2 >> 7, k = r2 & 127;
            const float* s = (m == 0) ? w_root : (w_rel + (size_t)(m - 1) * H * H);
            w3T[i2] = (_Float16)s[(size_t)k * H + c];
        }
    }
}

__device__ __forceinline__ f16x8 cvt8(float4 v0, float4 v1) {
    f16x8 t;
    t[0] = (_Float16)v0.x; t[1] = (_Float16)v0.y; t[2] = (_Float16)v0.z; t[3] = (_Float16)v0.w;
    t[4] = (_Float16)v1.x; t[5] = (_Float16)v1.y; t[6] = (_Float16)v1.z; t[7] = (_Float16)v1.w;
    return t;
}

// ---------------- big MFMA GEMM v2: barrier-free register streaming --------------
// C16 = fp16(leakyrelu(A[M,768] @ W + b)). Memory-bound (A fp32 = 153.6 MB read
// once; W is 196 KB, L2-hot). Old version: LDS double-buffer + vmcnt(0)+barrier
// every 32-k step -> only ~40cy of compute to hide ~900cy HBM latency -> 900 GB/s.
// v2: each wave owns a 32x128 tile fully in registers, A-frags straight from
// global (cvt fp32->f16 in regs), B-frags from the packed wInT (L2 hits), 1-deep
// register prefetch, NO LDS, NO barriers. Waves slip independently -> MLP limited
// only by vmcnt depth, not by the block-wide drain.
__global__ __launch_bounds__(256, 2) void gemm_big(const float* __restrict__ A,
    const _Float16* __restrict__ WP, const float* __restrict__ bias,
    _Float16* __restrict__ C16, int M, int K)
{
    const int tid = threadIdx.x;
    const int w   = tid >> 6;
    const int l   = tid & 63;
    const int l15 = l & 15;
    const int q   = l >> 4;
    const int brow = blockIdx.x * 128 + w * 32;

    // A fragment rows (lane l15 = row within 16-row frag, q*8 = k offset)
    int r0 = brow + l15;      if (r0 >= M) r0 = M - 1;
    int r1 = brow + 16 + l15; if (r1 >= M) r1 = M - 1;
    const float* ap0 = A + (size_t)r0 * K + q * 8;
    const float* ap1 = A + (size_t)r1 * K + q * 8;
    // packed B: step s, frag j -> WP + s*4*H*8 + (q*H + j*16 + l15)*8
    const _Float16* bp = WP + ((size_t)q * H + l15) * 8;

    float bj[8];
#pragma unroll
    for (int j = 0; j < 8; j++) bj[j] = bias[j * 16 + l15];

    f32x4 acc[2][8];
    const f32x4 z4 = {0.f, 0.f, 0.f, 0.f};
#pragma unroll
    for (int i = 0; i < 2; i++)
#pragma unroll
        for (int j = 0; j < 8; j++) acc[i][j] = z4;

    // prologue: step-0 operands
    float4 a00 = *(const float4*)(ap0);
    float4 a01 = *(const float4*)(ap0 + 4);
    float4 a10 = *(const float4*)(ap1);
    float4 a11 = *(const float4*)(ap1 + 4);
    f16x8 bf[8];
#pragma unroll
    for (int j = 0; j < 8; j++) bf[j] = *(const f16x8*)(bp + j * 128);

    const int steps = K / 32;             // 24
#pragma unroll 2
    for (int s = 0; s < steps; s++) {
        const bool more = (s + 1) < steps;
        float4 na00, na01, na10, na11; f16x8 nbf[8];
        if (more) {                        // 12 independent loads in flight during MFMAs
            const int k0 = (s + 1) * 32;
            na00 = *(const float4*)(ap0 + k0);
            na01 = *(const float4*)(ap0 + k0 + 4);
            na10 = *(const float4*)(ap1 + k0);
            na11 = *(const float4*)(ap1 + k0 + 4);
            const _Float16* nb = bp + (size_t)(s + 1) * 4 * H * 8;
#pragma unroll
            for (int j = 0; j < 8; j++) nbf[j] = *(const f16x8*)(nb + j * 128);
        }
        f16x8 af0 = cvt8(a00, a01);
        f16x8 af1 = cvt8(a10, a11);
#pragma unroll
        for (int j = 0; j < 8; j++) {
            acc[0][j] = __builtin_amdgcn_mfma_f32_16x16x32_f16(af0, bf[j], acc[0][j], 0, 0, 0);
            acc[1][j] = __builtin_amdgcn_mfma_f32_16x16x32_f16(af1, bf[j], acc[1][j], 0, 0, 0);
        }
        if (more) {
            a00 = na00; a01 = na01; a10 = na10; a11 = na11;
#pragma unroll
            for (int j = 0; j < 8; j++) bf[j] = nbf[j];
        }
    }

    // epilogue: bias + leaky, fp16 store (C frag: row = q*4+rg, col = j*16+l15)
#pragma unroll
    for (int i = 0; i < 2; i++)
#pragma unroll
        for (int rg = 0; rg < 4; rg++) {
            int row = brow + i * 16 + q * 4 + rg;
            if (row < M) {
#pragma unroll
                for (int j = 0; j < 8; j++) {
                    float v = acc[i][j][rg] + bj[j];
                    v = (v >= 0.f) ? v : 0.01f * v;
                    C16[(size_t)row * H + j * 16 + l15] = (_Float16)v;
                }
            }
        }
}

// ---------------- fused per-layer GEMM: B3 in regs, x software-pipelined ----------
// y = x@w_root + b (fp32); h_r = x@w_rel[r] (fp16). 512 threads = 8 waves x 16
// cols (full 128). Grid-stride over 16-row tiles; next tile's x-frags loaded
// before current tile's MFMAs (small reg arrays -> promoted).
__global__ __launch_bounds__(512) void gemm3(const _Float16* __restrict__ X16,
    const _Float16* __restrict__ W3, const float* __restrict__ bias,
    float* __restrict__ Y, _Float16* __restrict__ Hh, int M, int mtiles,
    size_t NH)
{
    const int w   = threadIdx.x >> 6;
    const int l   = threadIdx.x & 63;
    const int l15 = l & 15;
    const int q   = l >> 4;
    const int col = w * 16 + l15;

    f16x8 bf[3][4];
#pragma unroll
    for (int m = 0; m < 3; m++) {
        const _Float16* wpp = W3 + (size_t)m * H * H + (size_t)col * H + q * 8;
#pragma unroll
        for (int c = 0; c < 4; c++) bf[m][c] = *(const f16x8*)(wpp + c * 32);
    }
    const float bj = bias[col];

    int t = blockIdx.x;
    if (t >= mtiles) return;
    f16x8 xf[4];
    {
        const _Float16* xp = X16 + ((size_t)t * 16 + l15) * H + q * 8;
#pragma unroll
        for (int c = 0; c < 4; c++) xf[c] = *(const f16x8*)(xp + c * 32);
    }

    const f32x4 z4 = {0.f, 0.f, 0.f, 0.f};
    while (true) {
        int tn = t + gridDim.x;
        bool more = tn < mtiles;
        f16x8 xnf[4];
        if (more) {
            const _Float16* xp = X16 + ((size_t)tn * 16 + l15) * H + q * 8;
#pragma unroll
            for (int c = 0; c < 4; c++) xnf[c] = *(const f16x8*)(xp + c * 32);
        }

        f32x4 a0 = z4, a1 = z4, a2 = z4;
#pragma unroll
        for (int c = 0; c < 4; c++) {
            a0 = __builtin_amdgcn_mfma_f32_16x16x32_f16(xf[c], bf[0][c], a0, 0, 0, 0);
            a1 = __builtin_amdgcn_mfma_f32_16x16x32_f16(xf[c], bf[1][c], a1, 0, 0, 0);
            a2 = __builtin_amdgcn_mfma_f32_16x16x32_f16(xf[c], bf[2][c], a2, 0, 0, 0);
        }

#pragma unroll
        for (int rg = 0; rg < 4; rg++) {
            int row = t * 16 + q * 4 + rg;
            if (row < M) {
                Y [(size_t)row * H + col]      = a0[rg] + bj;
                Hh[(size_t)row * H + col]      = (_Float16)a1[rg];
                Hh[NH + (size_t)row * H + col] = (_Float16)a2[rg];
            }
        }
        if (!more) break;
        t = tn;
#pragma unroll
        for (int c = 0; c < 4; c++) xf[c] = xnf[c];
    }
}

// ---------------- mean-aggregate gather -------------------------------------------
// xn[dst] = fp16( y[dst] + sum_r mean(h_r[src]) ). One wave per dst row.
// 4 edge slots x 16 col-lanes; per-lane DIRECT elist loads (same address within
// a slot group -> broadcast fetch; NO shfl in divergent flow — ds_bpermute
// returns 0 from inactive lanes, which silently corrupts. Learned round 6.)
// 2-deep unroll: two independent 16B h-row loads in flight.
__global__ __launch_bounds__(256) void gather_mean(const float* __restrict__ Y,
    const _Float16* __restrict__ h, const int* __restrict__ elist,
    const int* __restrict__ cnt, _Float16* __restrict__ xn, int N, size_t NH)
{
    int wv = blockIdx.x * 4 + (threadIdx.x >> 6);
    int l  = threadIdx.x & 63;
    if (wv >= N) return;

    int d0r = cnt[wv], d1r = cnt[N + wv];
    int d0 = d0r < CAP ? d0r : CAP;
    int d1 = d1r < CAP ? d1r : CAP;
    float inv0 = d0r > 0 ? 1.f / (float)d0r : 0.f;
    float inv1 = d1r > 0 ? 1.f / (float)d1r : 0.f;
    const int* l0 = elist + (size_t)wv * CAP;
    const int* l1 = elist + ((size_t)N + wv) * CAP;
    const int tot = d0 + d1;

    const int eo = l >> 4;          // edge slot 0..3
    const int c8 = (l & 15) * 8;    // 8-col group

    float acc[8];
#pragma unroll
    for (int j = 0; j < 8; j++) acc[j] = 0.f;

    for (int p = eo; p < tot; p += 8) {
        int pb = p + 4;
        bool fA = p < d0;
        int   sA  = fA ? l0[p] : l1[p - d0];
        float scA = fA ? inv0 : inv1;
        size_t hA = fA ? (size_t)0 : NH;
        f16x8 vA  = *(const f16x8*)&h[hA + (size_t)sA * H + c8];
        if (pb < tot) {
            bool fB = pb < d0;
            int   sB  = fB ? l0[pb] : l1[pb - d0];
            float scB = fB ? inv0 : inv1;
            size_t hB = fB ? (size_t)0 : NH;
            f16x8 vB  = *(const f16x8*)&h[hB + (size_t)sB * H + c8];
#pragma unroll
            for (int j = 0; j < 8; j++) acc[j] += scA * (float)vA[j] + scB * (float)vB[j];
        } else {
#pragma unroll
            for (int j = 0; j < 8; j++) acc[j] += scA * (float)vA[j];
        }
    }

    // convergent full-wave reduction across the 4 edge slots
#pragma unroll
    for (int j = 0; j < 8; j++) {
        acc[j] += __shfl_xor(acc[j], 16);
        acc[j] += __shfl_xor(acc[j], 32);
    }

    if (eo == 0) {
        float4 y0 = *(const float4*)&Y[(size_t)wv * H + c8];
        float4 y1 = *(const float4*)&Y[(size_t)wv * H + c8 + 4];
        f16x8 o;
        o[0] = (_Float16)(acc[0] + y0.x); o[1] = (_Float16)(acc[1] + y0.y);
        o[2] = (_Float16)(acc[2] + y0.z); o[3] = (_Float16)(acc[3] + y0.w);
        o[4] = (_Float16)(acc[4] + y1.x); o[5] = (_Float16)(acc[5] + y1.y);
        o[6] = (_Float16)(acc[6] + y1.z); o[7] = (_Float16)(acc[7] + y1.w);
        *(f16x8*)&xn[(size_t)wv * H + c8] = o;
    }
}

// ---------------- final projection: out[N,OUT] = X[N,128] @ Wo[128,OUT] + bo ------
__global__ __launch_bounds__(256) void out_gemm(const _Float16* __restrict__ X16,
    const float* __restrict__ Wo, const float* __restrict__ bo,
    float* __restrict__ out, int N, int OUT)
{
    int row = blockIdx.x * 4 + (threadIdx.x >> 6);
    int lane = threadIdx.x & 63;
    if (row >= N) return;
    float a0 = (float)X16[(size_t)row * H + lane];
    float a1 = (float)X16[(size_t)row * H + 64 + lane];
    for (int c = 0; c < OUT; c++) {
        float p = a0 * Wo[lane * OUT + c] + a1 * Wo[(64 + lane) * OUT + c];
        for (int off = 32; off > 0; off >>= 1) p += __shfl_down(p, off);
        if (lane == 0) out[(size_t)row * OUT + c] = p + bo[c];
    }
}

extern "C" void kernel_launch(void* const* d_in, const int* in_sizes, int n_in,
                              void* d_out, int out_size, void* d_ws, size_t ws_size,
                              hipStream_t stream) {
    const float* feature = (const float*)d_in[0];
    const int*   ei      = (const int*)d_in[1];   // [2,E]: src then dst
    const int*   et      = (const int*)d_in[2];   // [E]
    const float* w_in    = (const float*)d_in[3];
    const float* b_in    = (const float*)d_in[4];
    const float* w_rel   = (const float*)d_in[5];
    const float* w_root  = (const float*)d_in[6];
    const float* b_conv  = (const float*)d_in[7];
    const float* w_out   = (const float*)d_in[8];
    const float* b_out   = (const float*)d_in[9];

    const int HH   = in_sizes[4];                 // 128
    const int D_IN = in_sizes[3] / HH;            // 768
    const int N    = in_sizes[0] / D_IN;          // 50000
    const int E    = in_sizes[1] / 2;             // 600000
    const int R    = in_sizes[5] / (HH * HH);     // 2 (layout assumes 2)
    const int OUT  = in_sizes[9];                 // 3

    const size_t NH = (size_t)N * H;

    // workspace layout (16B-aligned segments)
    char* base = (char*)d_ws;
    _Float16* wInT = (_Float16*)base;                              // 128*K (packed)
    _Float16* w3T  = wInT + (size_t)D_IN * HH;                     // 3*128*128
    _Float16* x0   = w3T + (size_t)3 * HH * HH;                    // N*H fp16
    _Float16* x1   = x0 + NH;                                      // N*H fp16
    _Float16* h    = x1 + NH;                                      // R*N*H fp16
    float* y       = (float*)(h + (size_t)R * NH);                 // N*H fp32
    int* cnt       = (int*)(y + NH);                               // R*N
    int* elist     = cnt + (size_t)R * N;                          // R*N*CAP

    hipMemsetAsync(cnt, 0, sizeof(int) * (size_t)R * N, stream);
    prep_w<<<(D_IN * HH + 3 * HH * HH + 255) / 256, 256, 0, stream>>>(
        w_in, w_root, w_rel, wInT, w3T, D_IN);
    hist_fill<<<(E + 255) / 256, 256, 0, stream>>>(ei, ei + E, et, cnt, elist, E, N);

    // x0 = fp16(leakyrelu(feature @ w_in + b_in)) — barrier-free streaming GEMM
    gemm_big<<<(N + 127) / 128, 256, 0, stream>>>(feature, wInT, b_in, x0, N, D_IN);

    const int mtiles = (N + 15) / 16;             // 3125 exact for N=50000
    _Float16* xc = x0;
    _Float16* xo = x1;
    for (int layer = 0; layer < 2; layer++) {
        gemm3<<<1024, 512, 0, stream>>>(xc, w3T, b_conv, y, h, N, mtiles, NH);
        gather_mean<<<(N + 3) / 4, 256, 0, stream>>>(y, h, elist, cnt, xo, N, NH);
        _Float16* t = xc; xc = xo; xo = t;
    }

    out_gemm<<<(N + 3) / 4, 256, 0, stream>>>(xc, w_out, b_out, (float*)d_out, N, OUT);
}

// Round 3
// 450.859 us; speedup vs baseline: 1.0323x; 1.0120x over previous
//
#include <hip/hip_runtime.h>

#define H 128          // hidden dim (fixed by problem)
#define CAP 64         // max edges per (rel,dst) bucket

typedef _Float16 f16x8 __attribute__((ext_vector_type(8)));
typedef float    f32x4 __attribute__((ext_vector_type(4)));

// ---------------- edge bucketing: one pass, reused by both layers ----------------
__global__ __launch_bounds__(256) void hist_fill(const int* __restrict__ src,
    const int* __restrict__ dst, const int* __restrict__ et,
    int* __restrict__ cnt, int* __restrict__ elist, int E, int N)
{
    int e = blockIdx.x * 256 + threadIdx.x;
    if (e >= E) return;
    int s = src[e], d = dst[e], t = et[e];
    int b = t * N + d;
    int pos = atomicAdd(&cnt[b], 1);
    if (pos < CAP) elist[(size_t)b * CAP + pos] = s;
}

// ---------------- weight prep ----------------
// wInT: packed MFMA-B-fragment order: wpk[((k>>3)*H + c)*8 + (k&7)] = w_in[k*H+c]
// so a wave's B-frag load (lane l15=col, q=k-group) is 4x256B contiguous segments.
// w3T: plain [col][k] transpose (consumed from regs in gemm3, layout unchanged).
__global__ __launch_bounds__(256) void prep_w(const float* __restrict__ w_in,
    const float* __restrict__ w_root, const float* __restrict__ w_rel,
    _Float16* __restrict__ wInT, _Float16* __restrict__ w3T, int K)
{
    int idx = blockIdx.x * 256 + threadIdx.x;
    int tot1 = K * H;
    if (idx < tot1) {
        int k = idx >> 7, c = idx & 127;               // input order: coalesced read
        int o = ((k >> 3) << 10) + (c << 3) + (k & 7); // ((k/8)*H + c)*8 + k%8
        wInT[o] = (_Float16)w_in[idx];
    } else {
        int i2 = idx - tot1;
        if (i2 < 3 * H * H) {
            int m = i2 / (H * H), r2 = i2 - m * (H * H);
            int c = r2 >> 7, k = r2 & 127;
            const float* s = (m == 0) ? w_root : (w_rel + (size_t)(m - 1) * H * H);
            w3T[i2] = (_Float16)s[(size_t)k * H + c];
        }
    }
}

__device__ __forceinline__ f16x8 cvt8(float4 v0, float4 v1) {
    f16x8 t;
    t[0] = (_Float16)v0.x; t[1] = (_Float16)v0.y; t[2] = (_Float16)v0.z; t[3] = (_Float16)v0.w;
    t[4] = (_Float16)v1.x; t[5] = (_Float16)v1.y; t[6] = (_Float16)v1.z; t[7] = (_Float16)v1.w;
    return t;
}

// ---------------- big MFMA GEMM v2: barrier-free register streaming --------------
// C16 = fp16(leakyrelu(A[M,768] @ W + b)). Memory-bound (A fp32 = 153.6 MB read
// once; W is 196 KB, L2-hot). Each wave owns a 32x128 tile fully in registers,
// A-frags straight from global (cvt fp32->f16 in regs), B-frags from packed wInT
// (L2 hits), 1-deep register prefetch, NO LDS, NO barriers.
__global__ __launch_bounds__(256, 2) void gemm_big(const float* __restrict__ A,
    const _Float16* __restrict__ WP, const float* __restrict__ bias,
    _Float16* __restrict__ C16, int M, int K)
{
    const int tid = threadIdx.x;
    const int w   = tid >> 6;
    const int l   = tid & 63;
    const int l15 = l & 15;
    const int q   = l >> 4;
    const int brow = blockIdx.x * 128 + w * 32;

    // A fragment rows (lane l15 = row within 16-row frag, q*8 = k offset)
    int r0 = brow + l15;      if (r0 >= M) r0 = M - 1;
    int r1 = brow + 16 + l15; if (r1 >= M) r1 = M - 1;
    const float* ap0 = A + (size_t)r0 * K + q * 8;
    const float* ap1 = A + (size_t)r1 * K + q * 8;
    // packed B: step s, frag j -> WP + s*4*H*8 + (q*H + j*16 + l15)*8
    const _Float16* bp = WP + ((size_t)q * H + l15) * 8;

    float bj[8];
#pragma unroll
    for (int j = 0; j < 8; j++) bj[j] = bias[j * 16 + l15];

    f32x4 acc[2][8];
    const f32x4 z4 = {0.f, 0.f, 0.f, 0.f};
#pragma unroll
    for (int i = 0; i < 2; i++)
#pragma unroll
        for (int j = 0; j < 8; j++) acc[i][j] = z4;

    // prologue: step-0 operands
    float4 a00 = *(const float4*)(ap0);
    float4 a01 = *(const float4*)(ap0 + 4);
    float4 a10 = *(const float4*)(ap1);
    float4 a11 = *(const float4*)(ap1 + 4);
    f16x8 bf[8];
#pragma unroll
    for (int j = 0; j < 8; j++) bf[j] = *(const f16x8*)(bp + j * 128);

    const int steps = K / 32;             // 24
#pragma unroll 2
    for (int s = 0; s < steps; s++) {
        const bool more = (s + 1) < steps;
        float4 na00, na01, na10, na11; f16x8 nbf[8];
        if (more) {                        // 12 independent loads in flight during MFMAs
            const int k0 = (s + 1) * 32;
            na00 = *(const float4*)(ap0 + k0);
            na01 = *(const float4*)(ap0 + k0 + 4);
            na10 = *(const float4*)(ap1 + k0);
            na11 = *(const float4*)(ap1 + k0 + 4);
            const _Float16* nb = bp + (size_t)(s + 1) * 4 * H * 8;
#pragma unroll
            for (int j = 0; j < 8; j++) nbf[j] = *(const f16x8*)(nb + j * 128);
        }
        f16x8 af0 = cvt8(a00, a01);
        f16x8 af1 = cvt8(a10, a11);
#pragma unroll
        for (int j = 0; j < 8; j++) {
            acc[0][j] = __builtin_amdgcn_mfma_f32_16x16x32_f16(af0, bf[j], acc[0][j], 0, 0, 0);
            acc[1][j] = __builtin_amdgcn_mfma_f32_16x16x32_f16(af1, bf[j], acc[1][j], 0, 0, 0);
        }
        if (more) {
            a00 = na00; a01 = na01; a10 = na10; a11 = na11;
#pragma unroll
            for (int j = 0; j < 8; j++) bf[j] = nbf[j];
        }
    }

    // epilogue: bias + leaky, fp16 store (C frag: row = q*4+rg, col = j*16+l15)
#pragma unroll
    for (int i = 0; i < 2; i++)
#pragma unroll
        for (int rg = 0; rg < 4; rg++) {
            int row = brow + i * 16 + q * 4 + rg;
            if (row < M) {
#pragma unroll
                for (int j = 0; j < 8; j++) {
                    float v = acc[i][j][rg] + bj[j];
                    v = (v >= 0.f) ? v : 0.01f * v;
                    C16[(size_t)row * H + j * 16 + l15] = (_Float16)v;
                }
            }
        }
}

// ---------------- fused per-layer GEMM: B3 in regs, x software-pipelined ----------
// y = x@w_root + b (fp32); h_r = x@w_rel[r] (fp16). 512 threads = 8 waves x 16
// cols (full 128). Grid-stride over 16-row tiles; next tile's x-frags loaded
// before current tile's MFMAs (small reg arrays -> promoted).
__global__ __launch_bounds__(512) void gemm3(const _Float16* __restrict__ X16,
    const _Float16* __restrict__ W3, const float* __restrict__ bias,
    float* __restrict__ Y, _Float16* __restrict__ Hh, int M, int mtiles,
    size_t NH)
{
    const int w   = threadIdx.x >> 6;
    const int l   = threadIdx.x & 63;
    const int l15 = l & 15;
    const int q   = l >> 4;
    const int col = w * 16 + l15;

    f16x8 bf[3][4];
#pragma unroll
    for (int m = 0; m < 3; m++) {
        const _Float16* wpp = W3 + (size_t)m * H * H + (size_t)col * H + q * 8;
#pragma unroll
        for (int c = 0; c < 4; c++) bf[m][c] = *(const f16x8*)(wpp + c * 32);
    }
    const float bj = bias[col];

    int t = blockIdx.x;
    if (t >= mtiles) return;
    f16x8 xf[4];
    {
        const _Float16* xp = X16 + ((size_t)t * 16 + l15) * H + q * 8;
#pragma unroll
        for (int c = 0; c < 4; c++) xf[c] = *(const f16x8*)(xp + c * 32);
    }

    const f32x4 z4 = {0.f, 0.f, 0.f, 0.f};
    while (true) {
        int tn = t + gridDim.x;
        bool more = tn < mtiles;
        f16x8 xnf[4];
        if (more) {
            const _Float16* xp = X16 + ((size_t)tn * 16 + l15) * H + q * 8;
#pragma unroll
            for (int c = 0; c < 4; c++) xnf[c] = *(const f16x8*)(xp + c * 32);
        }

        f32x4 a0 = z4, a1 = z4, a2 = z4;
#pragma unroll
        for (int c = 0; c < 4; c++) {
            a0 = __builtin_amdgcn_mfma_f32_16x16x32_f16(xf[c], bf[0][c], a0, 0, 0, 0);
            a1 = __builtin_amdgcn_mfma_f32_16x16x32_f16(xf[c], bf[1][c], a1, 0, 0, 0);
            a2 = __builtin_amdgcn_mfma_f32_16x16x32_f16(xf[c], bf[2][c], a2, 0, 0, 0);
        }

#pragma unroll
        for (int rg = 0; rg < 4; rg++) {
            int row = t * 16 + q * 4 + rg;
            if (row < M) {
                Y [(size_t)row * H + col]      = a0[rg] + bj;
                Hh[(size_t)row * H + col]      = (_Float16)a1[rg];
                Hh[NH + (size_t)row * H + col] = (_Float16)a2[rg];
            }
        }
        if (!more) break;
        t = tn;
#pragma unroll
        for (int c = 0; c < 4; c++) xf[c] = xnf[c];
    }
}

// ---------------- mean-aggregate gather (+ optional fused output projection) ------
// xn[dst] = fp16( y[dst] + sum_r mean(h_r[src]) ). One wave per dst row.
// 4 edge slots x 16 col-lanes; per-lane DIRECT elist loads (same address within
// a slot group -> broadcast fetch; NO shfl in divergent flow — ds_bpermute
// returns 0 from inactive lanes, which silently corrupts. Learned round 6.)
// 4-deep unroll: four independent 16B h-row loads in flight (mean degree ~12 =>
// typical row is ONE L3 round trip instead of two).
// DO_OUT: instead of storing xn, fuse out[dst] = (y+agg) @ Wo + bo in-register
// (all lanes hold the reduced acc after the convergent xor-16/32 — project 8
// cols/lane, then convergent xor-1/2/4/8 over the 16 col groups). Kills the
// out_gemm kernel + 12.8MB xn write + 12.8MB re-read. OUT==3 assumed.
template<int DO_OUT>
__global__ __launch_bounds__(256) void gather_mean(const float* __restrict__ Y,
    const _Float16* __restrict__ h, const int* __restrict__ elist,
    const int* __restrict__ cnt, _Float16* __restrict__ xn, int N, size_t NH,
    const float* __restrict__ Wo, const float* __restrict__ bo,
    float* __restrict__ out)
{
    int wv = blockIdx.x * 4 + (threadIdx.x >> 6);
    int l  = threadIdx.x & 63;
    if (wv >= N) return;

    int d0r = cnt[wv], d1r = cnt[N + wv];
    int d0 = d0r < CAP ? d0r : CAP;
    int d1 = d1r < CAP ? d1r : CAP;
    float inv0 = d0r > 0 ? 1.f / (float)d0r : 0.f;
    float inv1 = d1r > 0 ? 1.f / (float)d1r : 0.f;
    const int* l0 = elist + (size_t)wv * CAP;
    const int* l1 = elist + ((size_t)N + wv) * CAP;
    const int tot = d0 + d1;

    const int eo = l >> 4;          // edge slot 0..3
    const int c8 = (l & 15) * 8;    // 8-col group

    // per-lane Wo rows (L1-hot broadcast across eo replicas) for fused projection
    float wo0[8], wo1[8], wo2[8];
    if (DO_OUT) {
#pragma unroll
        for (int j = 0; j < 8; j++) {
            wo0[j] = Wo[(c8 + j) * 3 + 0];
            wo1[j] = Wo[(c8 + j) * 3 + 1];
            wo2[j] = Wo[(c8 + j) * 3 + 2];
        }
    }

    float acc[8];
#pragma unroll
    for (int j = 0; j < 8; j++) acc[j] = 0.f;

    const f16x8 zv = {};
    for (int p = eo; p < tot; p += 16) {
        int p1 = p + 4, p2 = p + 8, p3 = p + 12;
        // slot 0 always valid
        bool fA = p < d0;
        int   sA  = fA ? l0[p] : l1[p - d0];
        float scA = fA ? inv0 : inv1;
        f16x8 vA  = *(const f16x8*)&h[(fA ? (size_t)0 : NH) + (size_t)sA * H + c8];
        f16x8 vB = zv, vC = zv, vD = zv;
        float scB = 0.f, scC = 0.f, scD = 0.f;
        if (p1 < tot) {
            bool f = p1 < d0;
            int s = f ? l0[p1] : l1[p1 - d0];
            scB = f ? inv0 : inv1;
            vB = *(const f16x8*)&h[(f ? (size_t)0 : NH) + (size_t)s * H + c8];
        }
        if (p2 < tot) {
            bool f = p2 < d0;
            int s = f ? l0[p2] : l1[p2 - d0];
            scC = f ? inv0 : inv1;
            vC = *(const f16x8*)&h[(f ? (size_t)0 : NH) + (size_t)s * H + c8];
        }
        if (p3 < tot) {
            bool f = p3 < d0;
            int s = f ? l0[p3] : l1[p3 - d0];
            scD = f ? inv0 : inv1;
            vD = *(const f16x8*)&h[(f ? (size_t)0 : NH) + (size_t)s * H + c8];
        }
#pragma unroll
        for (int j = 0; j < 8; j++)
            acc[j] += scA * (float)vA[j] + scB * (float)vB[j]
                    + scC * (float)vC[j] + scD * (float)vD[j];
    }

    // convergent full-wave reduction across the 4 edge slots
#pragma unroll
    for (int j = 0; j < 8; j++) {
        acc[j] += __shfl_xor(acc[j], 16);
        acc[j] += __shfl_xor(acc[j], 32);
    }

    // y add (all lanes: eo-replicated addresses -> broadcast fetch)
    float4 y0 = *(const float4*)&Y[(size_t)wv * H + c8];
    float4 y1 = *(const float4*)&Y[(size_t)wv * H + c8 + 4];
    float xv[8];
    xv[0] = acc[0] + y0.x; xv[1] = acc[1] + y0.y;
    xv[2] = acc[2] + y0.z; xv[3] = acc[3] + y0.w;
    xv[4] = acc[4] + y1.x; xv[5] = acc[5] + y1.y;
    xv[6] = acc[6] + y1.z; xv[7] = acc[7] + y1.w;

    if (DO_OUT) {
        float p0 = 0.f, p1 = 0.f, p2 = 0.f;
#pragma unroll
        for (int j = 0; j < 8; j++) {
            p0 += xv[j] * wo0[j];
            p1 += xv[j] * wo1[j];
            p2 += xv[j] * wo2[j];
        }
        // convergent reduction over the 16 col groups (bits 0..3 of lane)
#pragma unroll
        for (int off = 1; off <= 8; off <<= 1) {
            p0 += __shfl_xor(p0, off);
            p1 += __shfl_xor(p1, off);
            p2 += __shfl_xor(p2, off);
        }
        if (l == 0) {
            out[(size_t)wv * 3 + 0] = p0 + bo[0];
            out[(size_t)wv * 3 + 1] = p1 + bo[1];
            out[(size_t)wv * 3 + 2] = p2 + bo[2];
        }
    } else {
        if (eo == 0) {
            f16x8 o;
#pragma unroll
            for (int j = 0; j < 8; j++) o[j] = (_Float16)xv[j];
            *(f16x8*)&xn[(size_t)wv * H + c8] = o;
        }
    }
}

// ---------------- final projection (fallback when OUT != 3) ----------------------
__global__ __launch_bounds__(256) void out_gemm(const _Float16* __restrict__ X16,
    const float* __restrict__ Wo, const float* __restrict__ bo,
    float* __restrict__ out, int N, int OUT)
{
    int row = blockIdx.x * 4 + (threadIdx.x >> 6);
    int lane = threadIdx.x & 63;
    if (row >= N) return;
    float a0 = (float)X16[(size_t)row * H + lane];
    float a1 = (float)X16[(size_t)row * H + 64 + lane];
    for (int c = 0; c < OUT; c++) {
        float p = a0 * Wo[lane * OUT + c] + a1 * Wo[(64 + lane) * OUT + c];
        for (int off = 32; off > 0; off >>= 1) p += __shfl_down(p, off);
        if (lane == 0) out[(size_t)row * OUT + c] = p + bo[c];
    }
}

extern "C" void kernel_launch(void* const* d_in, const int* in_sizes, int n_in,
                              void* d_out, int out_size, void* d_ws, size_t ws_size,
                              hipStream_t stream) {
    const float* feature = (const float*)d_in[0];
    const int*   ei      = (const int*)d_in[1];   // [2,E]: src then dst
    const int*   et      = (const int*)d_in[2];   // [E]
    const float* w_in    = (const float*)d_in[3];
    const float* b_in    = (const float*)d_in[4];
    const float* w_rel   = (const float*)d_in[5];
    const float* w_root  = (const float*)d_in[6];
    const float* b_conv  = (const float*)d_in[7];
    const float* w_out   = (const float*)d_in[8];
    const float* b_out   = (const float*)d_in[9];

    const int HH   = in_sizes[4];                 // 128
    const int D_IN = in_sizes[3] / HH;            // 768
    const int N    = in_sizes[0] / D_IN;          // 50000
    const int E    = in_sizes[1] / 2;             // 600000
    const int R    = in_sizes[5] / (HH * HH);     // 2 (layout assumes 2)
    const int OUT  = in_sizes[9];                 // 3

    const size_t NH = (size_t)N * H;

    // workspace layout (16B-aligned segments)
    char* base = (char*)d_ws;
    _Float16* wInT = (_Float16*)base;                              // 128*K (packed)
    _Float16* w3T  = wInT + (size_t)D_IN * HH;                     // 3*128*128
    _Float16* x0   = w3T + (size_t)3 * HH * HH;                    // N*H fp16
    _Float16* x1   = x0 + NH;                                      // N*H fp16
    _Float16* h    = x1 + NH;                                      // R*N*H fp16
    float* y       = (float*)(h + (size_t)R * NH);                 // N*H fp32
    int* cnt       = (int*)(y + NH);                               // R*N
    int* elist     = cnt + (size_t)R * N;                          // R*N*CAP

    hipMemsetAsync(cnt, 0, sizeof(int) * (size_t)R * N, stream);
    prep_w<<<(D_IN * HH + 3 * HH * HH + 255) / 256, 256, 0, stream>>>(
        w_in, w_root, w_rel, wInT, w3T, D_IN);
    hist_fill<<<(E + 255) / 256, 256, 0, stream>>>(ei, ei + E, et, cnt, elist, E, N);

    // x0 = fp16(leakyrelu(feature @ w_in + b_in)) — barrier-free streaming GEMM
    gemm_big<<<(N + 127) / 128, 256, 0, stream>>>(feature, wInT, b_in, x0, N, D_IN);

    const int mtiles = (N + 15) / 16;             // 3125 exact for N=50000
    const int gblocks = (N + 3) / 4;

    // layer 1
    gemm3<<<1024, 512, 0, stream>>>(x0, w3T, b_conv, y, h, N, mtiles, NH);
    gather_mean<0><<<gblocks, 256, 0, stream>>>(y, h, elist, cnt, x1, N, NH,
                                                nullptr, nullptr, nullptr);
    // layer 2 (+ fused output projection when OUT==3)
    gemm3<<<1024, 512, 0, stream>>>(x1, w3T, b_conv, y, h, N, mtiles, NH);
    if (OUT == 3) {
        gather_mean<1><<<gblocks, 256, 0, stream>>>(y, h, elist, cnt, x0, N, NH,
                                                    w_out, b_out, (float*)d_out);
    } else {
        gather_mean<0><<<gblocks, 256, 0, stream>>>(y, h, elist, cnt, x0, N, NH,
                                                    nullptr, nullptr, nullptr);
        out_gemm<<<gblocks, 256, 0, stream>>>(x0, w_out, b_out, (float*)d_out, N, OUT);
    }
}